// Round 7
// baseline (1166.667 us; speedup 1.0000x reference)
//
#include <hip/hip_runtime.h>
#include <stdint.h>

// Problem constants
#define CKP 128          // packed K (mk ; mk^2)
#define OCV 1024         // O*CV
#define NTOT 25920       // T*H*W
#define HW 1620
#define HWP 1664         // padded to 13*128
#define QT 128           // q tile
#define VT 256           // v tile
#define NC 64            // n chunk
#define NQT 13
#define NS 2
#define CHUNKS_TOTAL 405
#define CHUNK_SPLIT 203

typedef _Float16 f16x8 __attribute__((ext_vector_type(8)));
typedef _Float16 f16x4 __attribute__((ext_vector_type(4)));
typedef float f32x4 __attribute__((ext_vector_type(4)));

__device__ __forceinline__ void gload_lds16(const void* g, void* l) {
  __builtin_amdgcn_global_load_lds(
      (const __attribute__((address_space(1))) uint32_t*)g,
      (__attribute__((address_space(3))) uint32_t*)l, 16, 0, 0);
}

// ---- prep: memory_value fp32 -> mv2[b*4+vt][ch][idx] fp16, chunk-contiguous,
// PRE-SWIZZLED so k_main's MV stage is a pure linear 32KB stream per chunk.
// idx = v*8 + s (s = 16B slot); slot s holds source n-group j = s ^ (v&7).
__global__ void k_prep_mv2(const float* __restrict__ mv, _Float16* __restrict__ mv2) {
  int blk = blockIdx.x;                 // 3240 = (b*4+vt)*405 + ch
  int ch = blk % 405, g2 = blk / 405;
  int t = threadIdx.x;
  _Float16* outb = mv2 + (size_t)blk * 16384;
  #pragma unroll
  for (int r = 0; r < 8; ++r) {
    int idx = t + 256 * r;
    int v = idx >> 3, s = idx & 7, j = s ^ (v & 7);
    const float* src = mv + ((size_t)(g2 * 256 + v)) * NTOT + ch * 64 + j * 8;
    float4 a = *((const float4*)src);
    float4 c = *((const float4*)(src + 4));
    f16x8 o;
    o[0]=(_Float16)a.x; o[1]=(_Float16)a.y; o[2]=(_Float16)a.z; o[3]=(_Float16)a.w;
    o[4]=(_Float16)c.x; o[5]=(_Float16)c.y; o[6]=(_Float16)c.z; o[7]=(_Float16)c.w;
    *((f16x8*)(outb + (size_t)idx * 8)) = o;
  }
}

// ---- prep: memory_key -> MKpack[b][n][k] fp16 (rows mk ; mk^2)
__global__ void k_prep_mk(const float* __restrict__ mk, _Float16* __restrict__ mkp) {
  __shared__ _Float16 LT[64 * CKP];
  int b = blockIdx.y, n0 = blockIdx.x * 64;
  int c4 = threadIdx.x >> 6, nl = threadIdx.x & 63;
  for (int c = c4; c < 64; c += 4) {
    float v = mk[((size_t)(b * 64 + c)) * NTOT + n0 + nl];
    LT[nl * CKP + c]      = (_Float16)v;
    LT[nl * CKP + 64 + c] = (_Float16)(v * v);
  }
  __syncthreads();
  #pragma unroll
  for (int k = 0; k < 4; ++k) {
    int idx = threadIdx.x + 256 * k;
    int n = idx >> 4, c16 = idx & 15;
    *((uint4*)(mkp + ((size_t)b * NTOT + n0 + n) * CKP + c16 * 8)) =
        *((const uint4*)(&LT[n * CKP + c16 * 8]));
  }
}

// ---- prep: Qpack[b][q][k] fp16 (rows 2*qk*qe ; -qe), bsq fp32; pad q>=1620 with 0
__global__ void k_prep_q(const float* __restrict__ qk, const float* __restrict__ qe,
                         _Float16* __restrict__ qp, float* __restrict__ bsq) {
  __shared__ _Float16 LT[QT * CKP];
  int b = blockIdx.y, q0 = blockIdx.x * QT;
  int t = threadIdx.x;
  int q = q0 + t;
  bool valid = q < HW;
  float acc = 0.f;
  for (int c = 0; c < 64; ++c) {
    float a = valid ? qk[((size_t)(b * 64 + c)) * HW + q] : 0.f;
    float e = valid ? qe[((size_t)(b * 64 + c)) * HW + q] : 0.f;
    LT[t * CKP + c]      = (_Float16)(2.f * a * e);
    LT[t * CKP + 64 + c] = (_Float16)(-e);
    acc += e * a * a;
  }
  bsq[(size_t)b * HWP + q] = acc;
  __syncthreads();
  #pragma unroll
  for (int k = 0; k < 16; ++k) {
    int idx = t + 128 * k;
    int qq = idx >> 4, c16 = idx & 15;
    *((uint4*)(qp + ((size_t)b * HWP + q0 + qq) * CKP + c16 * 8)) =
        *((const uint4*)(&LT[qq * CKP + c16 * 8]));
  }
}

// ---- fused main (R4 structure) with ablation variants:
// V0: full, linear-MV (real output)     V1: no staging (compute-only)
// V2: stage-only, linear-MV             V3: stage-only, 51840B-stride gather-MV
template<int V>
__launch_bounds__(512, 1)
__global__ void k_main(const _Float16* __restrict__ mv2, const _Float16* __restrict__ mkp,
                       const _Float16* __restrict__ qp, const float* __restrict__ bsq,
                       const float* __restrict__ ms,
                       float* __restrict__ pO, float* __restrict__ lpart) {
  constexpr bool STAGE  = (V != 1);
  constexpr bool COMP   = (V <= 1);
  constexpr bool GATHER = (V == 3);

  const int wgid = blockIdx.x;
  const int xcd = wgid & 7, kk = wgid >> 3;    // kk in 0..25
  const int gsel = (kk >= NQT) ? 1 : 0;
  const int qt = kk - gsel * NQT;              // 0..12
  const int vt = ((xcd & 1) << 1) | gsel;      // 0..3
  const int bn = xcd >> 1;
  const int b = bn >> 1, nsp = bn & 1;

  const int tid = threadIdx.x;
  const int w = tid >> 6, l = tid & 63;
  const int l15 = l & 15, g = l >> 4;

  __shared__ _Float16 MVs[2][VT * NC];   // 2x32KB, linear dest
  __shared__ _Float16 MKs[2][NC * CKP];  // 2x16KB
  __shared__ _Float16 Ps[2][QT * NC];    // 2x16KB
  __shared__ float lred[QT * 8];

  const int qw = w & 3, nh = w >> 2;     // S-phase wave roles
  const int wv = w & 3, wq = w >> 2;     // readout roles

  const int cBeg = nsp ? CHUNK_SPLIT : 0;
  const int cEnd = nsp ? CHUNKS_TOTAL : CHUNK_SPLIT;

  // MV staging source: linear chunk-contiguous (mv2) or legacy strided gather
  const char* mvsrc = (const char*)mv2 + ((size_t)(b * 4 + vt) * 405) * 32768 + (size_t)tid * 16;
  const char* mvb3[4];
  if constexpr (GATHER) {
    #pragma unroll
    for (int k = 0; k < 4; ++k) {
      int idx = k * 512 + tid;
      int v = idx >> 3, s = idx & 7, j = s ^ (v & 7);
      mvb3[k] = (const char*)mv2 + ((size_t)(b * 512 + vt * 256 + v)) * (NTOT * 2) + j * 16;
    }
  }
  const char* mkb[2]; int dmk[2];
  #pragma unroll
  for (int k = 0; k < 2; ++k) {
    int idx = k * 512 + tid;
    int n = idx >> 4, s = idx & 15, j = s ^ (n & 7);
    mkb[k] = (const char*)(mkp + ((size_t)b * NTOT + n) * CKP + j * 8);
    dmk[k] = idx * 16;
  }
  const float* msb = ms + (size_t)b * NTOT + nh * 32 + g * 4;

  // Q fragments + bsq in registers (chunk-invariant)
  f16x8 qreg[2][4];
  float bq[2];
  if constexpr (COMP) {
    #pragma unroll
    for (int j = 0; j < 2; ++j) {
      int q_loc = qw * 32 + j * 16 + l15;
      const _Float16* qrow = qp + ((size_t)b * HWP + qt * QT + q_loc) * CKP;
      #pragma unroll
      for (int ks = 0; ks < 4; ++ks) qreg[j][ks] = *((const f16x8*)(qrow + (ks * 4 + g) * 8));
      bq[j] = bsq[(size_t)b * HWP + qt * QT + q_loc];
    }
  }

  f32x4 acc[4][4];
  #pragma unroll
  for (int i = 0; i < 4; ++i)
    #pragma unroll
    for (int j = 0; j < 4; ++j) acc[i][j] = (f32x4)0.f;
  float lp0 = 0.f, lp1 = 0.f;

  auto stage_mv = [&](int ch, int buf) {
    char* d = (char*)MVs[buf];
    if constexpr (GATHER) {
      size_t o = (size_t)ch * (NC * 2);
      #pragma unroll
      for (int k = 0; k < 4; ++k) gload_lds16(mvb3[k] + o, d + (k * 512 + tid) * 16);
    } else {
      const char* s = mvsrc + (size_t)ch * 32768;
      #pragma unroll
      for (int k = 0; k < 4; ++k) gload_lds16(s + k * 8192, d + (k * 512 + tid) * 16);
    }
  };
  auto stage_mk = [&](int ch, int buf) {
    size_t o = (size_t)ch * (NC * CKP * 2);
    char* d = (char*)MKs[buf];
    #pragma unroll
    for (int k = 0; k < 2; ++k) gload_lds16(mkb[k] + o, d + dmk[k]);
  };

  auto do_S = [&](int kb, int pb, float4 mA, float4 mB) {
    const _Float16* MKc = MKs[kb];
    f32x4 sacc[2][2];
    #pragma unroll
    for (int i2 = 0; i2 < 2; ++i2)
      #pragma unroll
      for (int j = 0; j < 2; ++j) sacc[i2][j] = (f32x4)0.f;
    #pragma unroll
    for (int ks = 0; ks < 4; ++ks) {
      f16x8 af[2];
      #pragma unroll
      for (int i2 = 0; i2 < 2; ++i2) {
        int n_loc = nh * 32 + i2 * 16 + l15;
        af[i2] = *((const f16x8*)(&MKc[n_loc * CKP + (((ks * 4 + g) ^ (n_loc & 7)) * 8)]));
      }
      #pragma unroll
      for (int i2 = 0; i2 < 2; ++i2)
        #pragma unroll
        for (int j = 0; j < 2; ++j)
          sacc[i2][j] = __builtin_amdgcn_mfma_f32_16x16x32_f16(af[i2], qreg[j][ks], sacc[i2][j], 0, 0, 0);
    }
    const float K = 0.125f * 1.44269504f;
    #pragma unroll
    for (int i2 = 0; i2 < 2; ++i2) {
      int nbase = nh * 32 + i2 * 16 + g * 4;
      float m0 = (i2 ? mB.x : mA.x) * K;
      float m1 = (i2 ? mB.y : mA.y) * K;
      float m2 = (i2 ? mB.z : mA.z) * K;
      float m3 = (i2 ? mB.w : mA.w) * K;
      #pragma unroll
      for (int j = 0; j < 2; ++j) {
        int q_loc = qw * 32 + j * 16 + l15;
        float bqv = bq[j];
        float p0 = exp2f((sacc[i2][j][0] - bqv) * m0);
        float p1 = exp2f((sacc[i2][j][1] - bqv) * m1);
        float p2 = exp2f((sacc[i2][j][2] - bqv) * m2);
        float p3 = exp2f((sacc[i2][j][3] - bqv) * m3);
        float psum = (p0 + p1) + (p2 + p3);
        if (j == 0) lp0 += psum; else lp1 += psum;
        f16x4 ph;
        ph[0]=(_Float16)p0; ph[1]=(_Float16)p1; ph[2]=(_Float16)p2; ph[3]=(_Float16)p3;
        int nb = nbase >> 3;
        int off4 = nbase & 7;
        *((f16x4*)(&Ps[pb][q_loc * NC + ((nb ^ (q_loc & 7)) * 8) + off4])) = ph;
      }
    }
  };

  auto do_RO = [&](int mb, int pb) {
    const _Float16* MVc = MVs[mb];
    const _Float16* Pc = Ps[pb];
    #pragma unroll
    for (int ks = 0; ks < 2; ++ks) {
      f16x8 av[4], bp[4];
      #pragma unroll
      for (int i = 0; i < 4; ++i) {
        int v_loc = wv * 64 + i * 16 + l15;
        av[i] = *((const f16x8*)(&MVc[v_loc * NC + (((ks * 4 + g) ^ (v_loc & 7)) * 8)]));
      }
      #pragma unroll
      for (int j = 0; j < 4; ++j) {
        int q_loc = wq * 64 + j * 16 + l15;
        bp[j] = *((const f16x8*)(&Pc[q_loc * NC + (((ks * 4 + g) ^ (q_loc & 7)) * 8)]));
      }
      #pragma unroll
      for (int i = 0; i < 4; ++i)
        #pragma unroll
        for (int j = 0; j < 4; ++j)
          acc[i][j] = __builtin_amdgcn_mfma_f32_16x16x32_f16(av[i], bp[j], acc[i][j], 0, 0, 0);
    }
  };

  // ---- prologue
  stage_mv(cBeg, 0);
  stage_mk(cBeg, 0);
  stage_mk(cBeg + 1, 1);
  if constexpr (V == 1) stage_mv(cBeg, 1);   // init buf1 for determinism (no in-loop staging)
  float4 mA0, mB0;
  if constexpr (COMP) {
    mA0 = *(const float4*)(msb + (size_t)cBeg * NC);
    mB0 = *(const float4*)(msb + (size_t)cBeg * NC + 16);
  }
  asm volatile("s_waitcnt vmcnt(0) lgkmcnt(0)" ::: "memory");
  __builtin_amdgcn_s_barrier();
  __builtin_amdgcn_sched_barrier(0);
  if constexpr (COMP) do_S(0, 0, mA0, mB0);
  asm volatile("s_waitcnt lgkmcnt(0)" ::: "memory");
  __builtin_amdgcn_s_barrier();
  __builtin_amdgcn_sched_barrier(0);

  // ---- main loop: one barrier per chunk (identical structure in all variants)
  const int numCh = cEnd - cBeg;
  for (int i = 0; i < numCh; ++i) {
    const int ch = cBeg + i;
    const int cur = i & 1, nxt = cur ^ 1;
    const bool hv = (ch + 1 < cEnd);
    float4 mA, mB;
    if constexpr (COMP) {
      if (hv) {
        mA = *(const float4*)(msb + (size_t)(ch + 1) * NC);
        mB = *(const float4*)(msb + (size_t)(ch + 1) * NC + 16);
      }
    }
    __builtin_amdgcn_sched_barrier(0);
    if constexpr (STAGE) {
      if (hv) stage_mv(ch + 1, nxt);
      if (ch + 2 < cEnd) stage_mk(ch + 2, cur);
    }
    if constexpr (COMP) {
      if (hv) do_S(nxt, nxt, mA, mB);
      do_RO(cur, cur);
    }
    asm volatile("s_waitcnt vmcnt(0) lgkmcnt(0)" ::: "memory");
    __builtin_amdgcn_s_barrier();
    __builtin_amdgcn_sched_barrier(0);
  }

  // ---- epilogue
  if constexpr (COMP) {
    {
      int q0a = qw * 32 + l15;
      lred[q0a * 8 + nh * 4 + g] = lp0;
      lred[(q0a + 16) * 8 + nh * 4 + g] = lp1;
    }
    __syncthreads();
    if (tid < QT) {
      float s = 0.f;
      #pragma unroll
      for (int j = 0; j < 8; ++j) s += lred[tid * 8 + j];
      lpart[((size_t)(b * NS + nsp)) * HWP + qt * QT + tid] = s;
    }
    #pragma unroll
    for (int i = 0; i < 4; ++i) {
      #pragma unroll
      for (int j = 0; j < 4; ++j) {
        #pragma unroll
        for (int r = 0; r < 4; ++r) {
          int v_glob = vt * VT + wv * 64 + i * 16 + g * 4 + r;
          int q_l = qt * QT + wq * 64 + j * 16 + l15;
          pO[(((size_t)(b * NS + nsp)) * OCV + v_glob) * HWP + q_l] = acc[i][j][r];
        }
      }
    }
  } else {
    if (tid == 0) lpart[((size_t)(b * NS + nsp)) * HWP + qt * QT] = lp0;
  }
}

// ---- final: out = sum_s O'_s / sum_s l_s
__global__ void k_reduce(const float* __restrict__ pO, const float* __restrict__ lpart,
                         float* __restrict__ out) {
  int i = blockIdx.x * 256 + threadIdx.x;
  int q4 = i % 405;
  int rest = i / 405;
  int v = rest & (OCV - 1);
  int b = rest >> 10;
  int q = q4 * 4;
  float apx = 0.f, apy = 0.f, apz = 0.f, apw = 0.f;
  float alx = 0.f, aly = 0.f, alz = 0.f, alw = 0.f;
  #pragma unroll
  for (int s = 0; s < NS; ++s) {
    const float4 p = *((const float4*)(pO + (((size_t)(b * NS + s)) * OCV + v) * HWP + q));
    const float4 lv = *((const float4*)(lpart + ((size_t)(b * NS + s)) * HWP + q));
    apx += p.x; apy += p.y; apz += p.z; apw += p.w;
    alx += lv.x; aly += lv.y; alz += lv.z; alw += lv.w;
  }
  float4 o;
  o.x = apx / alx; o.y = apy / aly; o.z = apz / alz; o.w = apw / alw;
  *((float4*)(out + ((size_t)b * OCV + v) * HW + q)) = o;
}

extern "C" void kernel_launch(void* const* d_in, const int* in_sizes, int n_in,
                              void* d_out, int out_size, void* d_ws, size_t ws_size,
                              hipStream_t stream) {
  const float* qk = (const float*)d_in[0];
  const float* qe = (const float*)d_in[1];
  const float* mk = (const float*)d_in[2];
  const float* ms = (const float*)d_in[3];
  const float* mv = (const float*)d_in[4];
  float* out = (float*)d_out;

  const size_t sz_mv2 = (size_t)2 * OCV * NTOT * 2;
  const size_t sz_mkp = (size_t)2 * NTOT * CKP * 2;
  const size_t sz_qp  = (size_t)2 * HWP * CKP * 2;
  const size_t sz_bsq = (size_t)2 * HWP * 4;
  const size_t sz_lp  = (size_t)2 * NS * HWP * 4;
  const size_t sz_pO  = (size_t)2 * NS * OCV * HWP * 4;
  const size_t need = sz_mv2 + sz_mkp + sz_qp + sz_bsq + 2 * (sz_lp + sz_pO);
  if (ws_size < need) return;

  char* p = (char*)d_ws;
  _Float16* mv2 = (_Float16*)p; p += sz_mv2;
  _Float16* mkp = (_Float16*)p; p += sz_mkp;
  _Float16* qp  = (_Float16*)p; p += sz_qp;
  float* bsqw   = (float*)p;    p += sz_bsq;
  float* lpart  = (float*)p;    p += sz_lp;
  float* pO     = (float*)p;    p += sz_pO;
  float* lp2    = (float*)p;    p += sz_lp;
  float* pO2    = (float*)p;

  k_prep_mv2<<<3240, 256, 0, stream>>>(mv, mv2);
  k_prep_mk<<<dim3(405, 2), 256, 0, stream>>>(mk, mkp);
  k_prep_q<<<dim3(NQT, 2), QT, 0, stream>>>(qk, qe, qp, bsqw);
  k_main<0><<<8 * 26, 512, 0, stream>>>(mv2, mkp, qp, bsqw, ms, pO, lpart);   // real
  k_reduce<<<3240, 256, 0, stream>>>(pO, lpart, out);
  k_main<1><<<8 * 26, 512, 0, stream>>>(mv2, mkp, qp, bsqw, ms, pO2, lp2);    // no staging
  k_main<2><<<8 * 26, 512, 0, stream>>>(mv2, mkp, qp, bsqw, ms, pO2, lp2);    // stage only, linear
  k_main<3><<<8 * 26, 512, 0, stream>>>(mv2, mkp, qp, bsqw, ms, pO2, lp2);    // stage only, gather
}

// Round 8
// 709.539 us; speedup vs baseline: 1.6443x; 1.6443x over previous
//
#include <hip/hip_runtime.h>
#include <stdint.h>

// Problem constants
#define CKP 128          // packed K (mk ; mk^2)
#define OCV 1024         // O*CV
#define NTOT 25920       // T*H*W
#define HW 1620
#define HWP 1664         // padded to 13*128
#define QT 128           // q tile
#define VT 256           // v tile
#define NC 32            // n chunk (68KB LDS -> 2 blocks/CU)
#define NQT 13
#define NS 4
#define CHUNKS_TOTAL 810 // NTOT/NC
#define CPN 203          // chunks per nsp split (last gets 201)

typedef _Float16 f16x8 __attribute__((ext_vector_type(8)));
typedef _Float16 f16x4 __attribute__((ext_vector_type(4)));
typedef float f32x4 __attribute__((ext_vector_type(4)));

__device__ __forceinline__ void gload_lds16(const void* g, void* l) {
  __builtin_amdgcn_global_load_lds(
      (const __attribute__((address_space(1))) uint32_t*)g,
      (__attribute__((address_space(3))) uint32_t*)l, 16, 0, 0);
}

// ---- prep: memory_value fp32 -> mv2[(b*4+vt)*810 + ch][idx] fp16, chunk-
// contiguous (16KB per chunk), PRE-SWIZZLED: idx = v*4 + s, slot s holds
// source n-group j = s ^ ((v>>1)&3)  (matches k_main's read-side XOR).
__global__ void k_prep_mv2(const float* __restrict__ mv, _Float16* __restrict__ mv2) {
  int blk = blockIdx.x;                 // 6480 = (b*4+vt)*810 + ch
  int ch = blk % 810, g2 = blk / 810;
  int t = threadIdx.x;
  _Float16* outb = mv2 + (size_t)blk * 8192;
  #pragma unroll
  for (int r = 0; r < 4; ++r) {
    int idx = t + 256 * r;              // [0,1024) 16B slots
    int v = idx >> 2, s = idx & 3, j = s ^ ((v >> 1) & 3);
    const float* src = mv + ((size_t)(g2 * 256 + v)) * NTOT + ch * 32 + j * 8;
    float4 a = *((const float4*)src);
    float4 c = *((const float4*)(src + 4));
    f16x8 o;
    o[0]=(_Float16)a.x; o[1]=(_Float16)a.y; o[2]=(_Float16)a.z; o[3]=(_Float16)a.w;
    o[4]=(_Float16)c.x; o[5]=(_Float16)c.y; o[6]=(_Float16)c.z; o[7]=(_Float16)c.w;
    *((f16x8*)(outb + (size_t)idx * 8)) = o;
  }
}

// ---- prep: memory_key -> MKpack[b][n][k] fp16 (rows mk ; mk^2)
__global__ void k_prep_mk(const float* __restrict__ mk, _Float16* __restrict__ mkp) {
  __shared__ _Float16 LT[64 * CKP];
  int b = blockIdx.y, n0 = blockIdx.x * 64;
  int c4 = threadIdx.x >> 6, nl = threadIdx.x & 63;
  for (int c = c4; c < 64; c += 4) {
    float v = mk[((size_t)(b * 64 + c)) * NTOT + n0 + nl];
    LT[nl * CKP + c]      = (_Float16)v;
    LT[nl * CKP + 64 + c] = (_Float16)(v * v);
  }
  __syncthreads();
  #pragma unroll
  for (int k = 0; k < 4; ++k) {
    int idx = threadIdx.x + 256 * k;
    int n = idx >> 4, c16 = idx & 15;
    *((uint4*)(mkp + ((size_t)b * NTOT + n0 + n) * CKP + c16 * 8)) =
        *((const uint4*)(&LT[n * CKP + c16 * 8]));
  }
}

// ---- prep: Qpack[b][q][k] fp16 (rows 2*qk*qe ; -qe), bsq fp32; pad q>=1620 with 0
__global__ void k_prep_q(const float* __restrict__ qk, const float* __restrict__ qe,
                         _Float16* __restrict__ qp, float* __restrict__ bsq) {
  __shared__ _Float16 LT[QT * CKP];
  int b = blockIdx.y, q0 = blockIdx.x * QT;
  int t = threadIdx.x;
  int q = q0 + t;
  bool valid = q < HW;
  float acc = 0.f;
  for (int c = 0; c < 64; ++c) {
    float a = valid ? qk[((size_t)(b * 64 + c)) * HW + q] : 0.f;
    float e = valid ? qe[((size_t)(b * 64 + c)) * HW + q] : 0.f;
    LT[t * CKP + c]      = (_Float16)(2.f * a * e);
    LT[t * CKP + 64 + c] = (_Float16)(-e);
    acc += e * a * a;
  }
  bsq[(size_t)b * HWP + q] = acc;
  __syncthreads();
  #pragma unroll
  for (int k = 0; k < 16; ++k) {
    int idx = t + 128 * k;
    int qq = idx >> 4, c16 = idx & 15;
    *((uint4*)(qp + ((size_t)b * HWP + q0 + qq) * CKP + c16 * 8)) =
        *((const uint4*)(&LT[qq * CKP + c16 * 8]));
  }
}

// ---- fused main. NC=32, LDS 68KB -> 2 blocks/CU (4 waves/SIMD).
// Grid 416 = 8 xcds x 52; xcd = b*4+nsp (shared MK stream per XCD,
// 13 qt-blocks share each MV stream). R4/R7 pipeline structure unchanged.
__launch_bounds__(512, 2)
__global__ void k_main(const _Float16* __restrict__ mv2, const _Float16* __restrict__ mkp,
                       const _Float16* __restrict__ qp, const float* __restrict__ bsq,
                       const float* __restrict__ ms,
                       float* __restrict__ pO, float* __restrict__ lpart) {
  const int wgid = blockIdx.x;
  const int xcd = wgid & 7, kk = wgid >> 3;    // kk in 0..51
  const int b = xcd >> 2, nsp = xcd & 3;
  const int vt = kk / NQT, qt = kk % NQT;

  const int tid = threadIdx.x;
  const int w = tid >> 6, l = tid & 63;
  const int l15 = l & 15, g = l >> 4;

  __shared__ _Float16 MVs[2][VT * NC];   // 2x16KB, linear dest (pre-swizzled src)
  __shared__ _Float16 MKs[2][NC * CKP];  // 2x8KB
  __shared__ _Float16 Ps[2][QT * NC];    // 2x8KB
  __shared__ float lred[QT * 8];

  const int qw = w & 3, nh = w >> 2;     // S-phase wave roles (nh: n-half of 16)
  const int wv = w & 3, wq = w >> 2;     // readout roles

  const int cBeg = nsp * CPN;
  int ce = cBeg + CPN; if (ce > CHUNKS_TOTAL) ce = CHUNKS_TOTAL;
  const int cEnd = ce;

  // MV staging source: linear chunk-contiguous stream (16KB/chunk)
  const char* mvsrc = (const char*)mv2 + ((size_t)(b * 4 + vt) * CHUNKS_TOTAL) * 16384
                    + (size_t)tid * 16;
  // MK tile: 32 rows x 128 f16 (256B) = 512 slots; j = s ^ (n&7).
  const char* mkb; int dmk;
  {
    int idx = tid;
    int n = idx >> 4, s = idx & 15, j = s ^ (n & 7);
    mkb = (const char*)(mkp + ((size_t)b * NTOT + n) * CKP + j * 8);
    dmk = idx * 16;
  }
  const float* msb = ms + (size_t)b * NTOT + nh * 16 + g * 4;

  // Q fragments + bsq in registers (chunk-invariant)
  f16x8 qreg[2][4];
  float bq[2];
  #pragma unroll
  for (int j = 0; j < 2; ++j) {
    int q_loc = qw * 32 + j * 16 + l15;
    const _Float16* qrow = qp + ((size_t)b * HWP + qt * QT + q_loc) * CKP;
    #pragma unroll
    for (int ks = 0; ks < 4; ++ks) qreg[j][ks] = *((const f16x8*)(qrow + (ks * 4 + g) * 8));
    bq[j] = bsq[(size_t)b * HWP + qt * QT + q_loc];
  }

  f32x4 acc[4][4];
  #pragma unroll
  for (int i = 0; i < 4; ++i)
    #pragma unroll
    for (int j = 0; j < 4; ++j) acc[i][j] = (f32x4)0.f;
  float lp0 = 0.f, lp1 = 0.f;

  auto stage_mv = [&](int ch, int buf) {
    const char* s = mvsrc + (size_t)ch * 16384;
    char* d = (char*)MVs[buf];
    #pragma unroll
    for (int k = 0; k < 2; ++k) gload_lds16(s + k * 8192, d + (size_t)tid * 16 + k * 8192);
  };
  auto stage_mk = [&](int ch, int buf) {
    size_t o = (size_t)ch * (NC * CKP * 2);
    gload_lds16(mkb + o, (char*)MKs[buf] + dmk);
  };

  // S = MK x Q over K=128 for a 32n x 128q tile; each wave: 16n x 32q.
  auto do_S = [&](int kb, int pb, float4 mA) {
    const _Float16* MKc = MKs[kb];
    f32x4 sacc[2];
    sacc[0] = (f32x4)0.f; sacc[1] = (f32x4)0.f;
    const int n_loc = nh * 16 + l15;
    #pragma unroll
    for (int ks = 0; ks < 4; ++ks) {
      f16x8 af = *((const f16x8*)(&MKc[n_loc * CKP + (((ks * 4 + g) ^ (n_loc & 7)) * 8)]));
      #pragma unroll
      for (int j = 0; j < 2; ++j)
        sacc[j] = __builtin_amdgcn_mfma_f32_16x16x32_f16(af, qreg[j][ks], sacc[j], 0, 0, 0);
    }
    const float K = 0.125f * 1.44269504f;
    const int nbase = nh * 16 + g * 4;
    float m0 = mA.x * K, m1 = mA.y * K, m2 = mA.z * K, m3 = mA.w * K;
    #pragma unroll
    for (int j = 0; j < 2; ++j) {
      int q_loc = qw * 32 + j * 16 + l15;
      float bqv = bq[j];
      float p0 = exp2f((sacc[j][0] - bqv) * m0);
      float p1 = exp2f((sacc[j][1] - bqv) * m1);
      float p2 = exp2f((sacc[j][2] - bqv) * m2);
      float p3 = exp2f((sacc[j][3] - bqv) * m3);
      float psum = (p0 + p1) + (p2 + p3);
      if (j == 0) lp0 += psum; else lp1 += psum;
      f16x4 ph;
      ph[0]=(_Float16)p0; ph[1]=(_Float16)p1; ph[2]=(_Float16)p2; ph[3]=(_Float16)p3;
      int nb = nbase >> 3;
      int off4 = nbase & 7;                       // 0 or 4
      int slot = nb ^ ((q_loc >> 1) & 3);
      *((f16x4*)(&Ps[pb][q_loc * NC + slot * 8 + off4])) = ph;
    }
  };

  // readout: 256v x 128q, K=32 (16 MFMA per wave per chunk)
  auto do_RO = [&](int mb, int pb) {
    const _Float16* MVc = MVs[mb];
    const _Float16* Pc = Ps[pb];
    f16x8 av[4], bp[4];
    #pragma unroll
    for (int i = 0; i < 4; ++i) {
      int v_loc = wv * 64 + i * 16 + l15;
      av[i] = *((const f16x8*)(&MVc[v_loc * NC + ((g ^ ((v_loc >> 1) & 3)) * 8)]));
    }
    #pragma unroll
    for (int j = 0; j < 4; ++j) {
      int q_loc = wq * 64 + j * 16 + l15;
      bp[j] = *((const f16x8*)(&Pc[q_loc * NC + ((g ^ ((q_loc >> 1) & 3)) * 8)]));
    }
    #pragma unroll
    for (int i = 0; i < 4; ++i)
      #pragma unroll
      for (int j = 0; j < 4; ++j)
        acc[i][j] = __builtin_amdgcn_mfma_f32_16x16x32_f16(av[i], bp[j], acc[i][j], 0, 0, 0);
  };

  // ---- prologue: stage MV+MK(cBeg), MK(cBeg+1); S(cBeg) -> Ps[0]
  stage_mv(cBeg, 0);
  stage_mk(cBeg, 0);
  if (cBeg + 1 < cEnd) stage_mk(cBeg + 1, 1);
  float4 mA0 = *(const float4*)(msb + (size_t)cBeg * NC);
  asm volatile("s_waitcnt vmcnt(0)" ::: "memory");
  __builtin_amdgcn_s_barrier();
  __builtin_amdgcn_sched_barrier(0);
  do_S(0, 0, mA0);
  asm volatile("s_waitcnt lgkmcnt(0)" ::: "memory");
  __builtin_amdgcn_s_barrier();
  __builtin_amdgcn_sched_barrier(0);

  // ---- main loop: [stage ch+1 MV, ch+2 MK] || S(ch+1) ; barrier ; RO(ch) ; barrier
  const int numCh = cEnd - cBeg;
  for (int i = 0; i < numCh; ++i) {
    const int ch = cBeg + i;
    const int cur = i & 1, nxt = cur ^ 1;
    const bool hv = (ch + 1 < cEnd);
    float4 mA;
    if (hv) mA = *(const float4*)(msb + (size_t)(ch + 1) * NC);
    __builtin_amdgcn_sched_barrier(0);
    if (hv) stage_mv(ch + 1, nxt);
    if (ch + 2 < cEnd) stage_mk(ch + 2, cur);
    if (hv) do_S(nxt, nxt, mA);
    do_RO(cur, cur);
    asm volatile("s_waitcnt vmcnt(0) lgkmcnt(0)" ::: "memory");
    __builtin_amdgcn_s_barrier();
    __builtin_amdgcn_sched_barrier(0);
  }

  // ---- epilogue: reduce l partials (8 contributors per q: nh x g)
  {
    int q0a = qw * 32 + l15;
    lred[q0a * 8 + nh * 4 + g] = lp0;
    lred[(q0a + 16) * 8 + nh * 4 + g] = lp1;
  }
  __syncthreads();
  if (tid < QT) {
    float s = 0.f;
    #pragma unroll
    for (int j = 0; j < 8; ++j) s += lred[tid * 8 + j];
    lpart[((size_t)(b * NS + nsp)) * HWP + qt * QT + tid] = s;
  }
  #pragma unroll
  for (int i = 0; i < 4; ++i) {
    #pragma unroll
    for (int j = 0; j < 4; ++j) {
      #pragma unroll
      for (int r = 0; r < 4; ++r) {
        int v_glob = vt * VT + wv * 64 + i * 16 + g * 4 + r;
        int q_l = qt * QT + wq * 64 + j * 16 + l15;
        pO[(((size_t)(b * NS + nsp)) * OCV + v_glob) * HWP + q_l] = acc[i][j][r];
      }
    }
  }
}

// ---- final: out = sum_s O'_s / sum_s l_s
__global__ void k_reduce(const float* __restrict__ pO, const float* __restrict__ lpart,
                         float* __restrict__ out) {
  int i = blockIdx.x * 256 + threadIdx.x;
  int q4 = i % 405;
  int rest = i / 405;
  int v = rest & (OCV - 1);
  int b = rest >> 10;
  int q = q4 * 4;
  float apx = 0.f, apy = 0.f, apz = 0.f, apw = 0.f;
  float alx = 0.f, aly = 0.f, alz = 0.f, alw = 0.f;
  #pragma unroll
  for (int s = 0; s < NS; ++s) {
    const float4 p = *((const float4*)(pO + (((size_t)(b * NS + s)) * OCV + v) * HWP + q));
    const float4 lv = *((const float4*)(lpart + ((size_t)(b * NS + s)) * HWP + q));
    apx += p.x; apy += p.y; apz += p.z; apw += p.w;
    alx += lv.x; aly += lv.y; alz += lv.z; alw += lv.w;
  }
  float4 o;
  o.x = apx / alx; o.y = apy / aly; o.z = apz / alz; o.w = apw / alw;
  *((float4*)(out + ((size_t)b * OCV + v) * HW + q)) = o;
}

extern "C" void kernel_launch(void* const* d_in, const int* in_sizes, int n_in,
                              void* d_out, int out_size, void* d_ws, size_t ws_size,
                              hipStream_t stream) {
  const float* qk = (const float*)d_in[0];
  const float* qe = (const float*)d_in[1];
  const float* mk = (const float*)d_in[2];
  const float* ms = (const float*)d_in[3];
  const float* mv = (const float*)d_in[4];
  float* out = (float*)d_out;

  const size_t sz_mv2 = (size_t)2 * OCV * NTOT * 2;
  const size_t sz_mkp = (size_t)2 * NTOT * CKP * 2;
  const size_t sz_qp  = (size_t)2 * HWP * CKP * 2;
  const size_t sz_bsq = (size_t)2 * HWP * 4;
  const size_t sz_lp  = (size_t)2 * NS * HWP * 4;
  const size_t sz_pO  = (size_t)2 * NS * OCV * HWP * 4;
  const size_t need = sz_mv2 + sz_mkp + sz_qp + sz_bsq + sz_lp + sz_pO;
  if (ws_size < need) return;

  char* p = (char*)d_ws;
  _Float16* mv2 = (_Float16*)p; p += sz_mv2;
  _Float16* mkp = (_Float16*)p; p += sz_mkp;
  _Float16* qp  = (_Float16*)p; p += sz_qp;
  float* bsqw   = (float*)p;    p += sz_bsq;
  float* lpart  = (float*)p;    p += sz_lp;
  float* pO     = (float*)p;

  k_prep_mv2<<<6480, 256, 0, stream>>>(mv, mv2);
  k_prep_mk<<<dim3(405, 2), 256, 0, stream>>>(mk, mkp);
  k_prep_q<<<dim3(NQT, 2), QT, 0, stream>>>(qk, qe, qp, bsqw);
  k_main<<<8 * 52, 512, 0, stream>>>(mv2, mkp, qp, bsqw, ms, pO, lpart);
  k_reduce<<<3240, 256, 0, stream>>>(pO, lpart, out);
}